// Round 5
// baseline (130.349 us; speedup 1.0000x reference)
//
#include <hip/hip_runtime.h>
#include <math.h>

#define PI_F     3.14159265358979f
#define TWOPI_F  6.283185307179586f
#define ALPHA_F  14.04f          // 2.34 * J, J = 6
#define NK       552960          // 720 * 768
#define NANG     720
#define NDET     768

// ---------- modified Bessel I0, Abramowitz-Stegun 9.8.1/9.8.2 (|eps|<2e-7 rel) ----
__device__ __forceinline__ float i0f(float x) {
    if (x < 3.75f) {
        float t = x * (1.0f / 3.75f);
        float t2 = t * t;
        return 1.0f + t2 * (3.5156229f + t2 * (3.0899424f + t2 * (1.2067492f +
                     t2 * (0.2659732f + t2 * (0.0360768f + t2 * 0.0045813f)))));
    } else {
        float ti = 3.75f / x;
        float p = 0.39894228f + ti * (0.01328592f + ti * (0.00225319f +
                  ti * (-0.00157565f + ti * (0.00916281f + ti * (-0.02057706f +
                  ti * (0.02635537f + ti * (-0.01647633f + ti * 0.00392377f)))))));
        return __expf(x) * rsqrtf(x) * p;
    }
}

// image-domain apodization value for index i (N=512, G=1024): arg>0 always here
__device__ __forceinline__ float apodf(int i, float inv_i0a) {
    float u = ((float)i - 256.0f) * (1.0f / 1024.0f);
    float pj = PI_F * 6.0f * u;
    float arg = ALPHA_F * ALPHA_F - pj * pj;
    float s = sqrtf(arg);
    float F = sinhf(s) / s * (6.0f * inv_i0a);
    return 1.0f / F;
}

// multiply complex v by i^k
__device__ __forceinline__ float2 mul_ipow(float2 v, int k) {
    switch (k & 3) {
        case 0:  return v;
        case 1:  return make_float2(-v.y,  v.x);
        case 2:  return make_float2(-v.x, -v.y);
        default: return make_float2( v.y, -v.x);
    }
}

// ---------- batched Stockham radix-2 FFT in LDS with twiddle table ----------------
// B contiguous FFTs of length N (layout src[b*N + j]). tw[j] = e^{i*sgn*2pi*j/N},
// j < N/2. LOGSKIP: number of leading stages already folded into the LDS layout
// (caller pre-staged the buffer as the output of those stages). Result ends in the
// returned pointer.
template<int N, int LOGN, int B, int T, int LOGSKIP>
__device__ __forceinline__ float2* stockham_b(float2* src, float2* dst,
                                              const float2* __restrict__ tw, int tid) {
    constexpr int HALF = N >> 1;
    int log2s = LOGSKIP;
    for (int n = (N >> LOGSKIP); n > 1; n >>= 1, ++log2s) {
        int h = n >> 1;
        int s = 1 << log2s;
        #pragma unroll
        for (int i = tid; i < B * HALF; i += T) {
            int bb = i >> (LOGN - 1);
            int j  = i & (HALF - 1);
            int q = j & (s - 1);
            int p = j >> log2s;
            float2 w = tw[p << log2s];
            float2* S = src + bb * N;
            float2* D = dst + bb * N;
            float2 a  = S[q + (p << log2s)];
            float2 b2 = S[q + ((p + h) << log2s)];
            float2 su = make_float2(a.x + b2.x, a.y + b2.y);
            float2 di = make_float2(a.x - b2.x, a.y - b2.y);
            D[q + ((2 * p) << log2s)]     = su;
            D[q + ((2 * p + 1) << log2s)] = make_float2(di.x * w.x - di.y * w.y,
                                                        di.x * w.y + di.y * w.x);
        }
        __syncthreads();
        float2* t = src; src = dst; dst = t;
    }
    return src;
}

// ---------- stage 1: row FFTs (apod + zero-pad stage-1 fold) ----------------------
// U[r][k2] = i^k2 * sum_c a[r][c] W1024^{c k2}. Upper 512 inputs are zero, so
// stage 1 folds into the load: bA[2c] = v, bA[2c+1] = v * tw[c].
__global__ __launch_bounds__(512) void fft_rows_kernel(const float* __restrict__ img,
                                                       float2* __restrict__ U) {
    __shared__ float2 bA[1024], bB[1024], tw[512];
    int r = blockIdx.x, t = threadIdx.x;
    {
        float ang = -TWOPI_F * (float)t * (1.0f / 1024.0f);
        float sn, cs; sincosf(ang, &sn, &cs);
        tw[t] = make_float2(cs, sn);
    }
    float inv_i0a = 1.0f / i0f(ALPHA_F);
    float ar = apodf(r, inv_i0a);
    __syncthreads();                                  // tw ready (needed for fold)
    {
        int c = t;
        float v = img[r * 512 + c] * ar * apodf(c, inv_i0a);
        float2 w = tw[c];
        bA[2 * c]     = make_float2(v, 0.0f);
        bA[2 * c + 1] = make_float2(v * w.x, v * w.y);
    }
    __syncthreads();
    float2* res = stockham_b<1024, 10, 1, 512, 1>(bA, bB, tw, t);   // 9 stages
    for (int k = t; k < 1024; k += 512)
        U[r * 1024 + k] = mul_ipow(res[k], k);
}

// ---------- stage 2: col FFTs, 2 columns/block, stage-1 fold ----------------------
// GT[k2*1024 + k1] == grid_hat[k1][k2] = i^k1/1024 * sum_r U[r][k2] W1024^{r k1}
__global__ __launch_bounds__(512) void fft_cols_kernel(const float2* __restrict__ U,
                                                       float2* __restrict__ GT) {
    __shared__ float2 bA[2048], bB[2048], tw[512];
    int c0 = blockIdx.x * 2, t = threadIdx.x;
    {
        float ang = -TWOPI_F * (float)t * (1.0f / 1024.0f);
        float sn, cs; sincosf(ang, &sn, &cs);
        tw[t] = make_float2(cs, sn);
    }
    __syncthreads();                                  // tw ready (needed for fold)
    #pragma unroll
    for (int it = 0; it < 2; ++it) {                  // 512 rows x 2 cols, coalesced pairs
        int i = t + it * 512;
        int rr = i >> 1, cc = i & 1;
        float2 v = U[rr * 1024 + c0 + cc];
        float2 w = tw[rr];
        float2* b = bA + cc * 1024;
        b[2 * rr]     = v;
        b[2 * rr + 1] = make_float2(v.x * w.x - v.y * w.y, v.x * w.y + v.y * w.x);
    }
    __syncthreads();
    float2* res = stockham_b<1024, 10, 2, 512, 1>(bA, bB, tw, t);   // 9 stages
    const float sc = 1.0f / 1024.0f;
    #pragma unroll
    for (int it = 0; it < 4; ++it) {
        int i = t + it * 512;
        int cc = i >> 10, k1 = i & 1023;
        float2 v = mul_ipow(res[cc * 1024 + k1], k1);
        GT[(c0 + cc) * 1024 + k1] = make_float2(v.x * sc, v.y * sc);
    }
}

// ---------- stage 3+4 fused: per-angle KB gather + length-768 inverse FFT ---------
// Block = one angle (XCD-swizzled: 90 contiguous angles per XCD -> sector fits the
// 4 MB per-XCD L2). Gather uses an even-aligned 8-tap window in the contiguous k1
// dim: 4x float4 loads per row instead of 6x float2 (out-of-window taps get w=0
// via the x<=0 clamp). Then 3x256-pt inverse Stockham + radix-3 combine.
__global__ __launch_bounds__(768) void gather_ifft_kernel(const float* __restrict__ ksp,
                                                          const float2* __restrict__ GT,
                                                          float* __restrict__ out) {
    __shared__ float2 fA[768], fB[768], tw[128];
    int t = threadIdx.x;
    int a = (blockIdx.x & 7) * 90 + (blockIdx.x >> 3);   // XCD-contiguous angles
    if (t < 128) {
        float ang = TWOPI_F * (float)t * (1.0f / 256.0f);   // inverse sign
        float sn, cs; sincosf(ang, &sn, &cs);
        tw[t] = make_float2(cs, sn);
    }

    int k = a * NDET + t;                    // this thread's k-point
    const float inv_i0a = 1.0f / i0f(ALPHA_F);
    float ky = ksp[k];
    float kx = ksp[NK + k];

    // dim 1 (contiguous k1, from ky): 8-tap even-aligned window
    float w1[8];
    int   off1[4];                           // byte offsets of the 4 float4 loads
    {
        float v = ky * (512.0f / PI_F);
        float q = v * (1.0f / 1024.0f);
        v = (q - floorf(q)) * 1024.0f;       // in [0,1024)
        int base = (int)floorf(v);
        int e = (base - 2) & ~1;             // even window start, covers base-2..base+3
        float fe = v - (float)e;             // in [2,4)
        #pragma unroll
        for (int m = 0; m < 8; ++m) {
            float u = fe - (float)m;
            float x = 1.0f - u * u * (1.0f / 9.0f);
            w1[m] = (x > 0.0f) ? i0f(ALPHA_F * sqrtf(x)) * inv_i0a : 0.0f;
        }
        #pragma unroll
        for (int l = 0; l < 4; ++l)
            off1[l] = ((e + 2 * l) & 1023) * 8;
    }
    // dim 2 (rows, from kx): exact 6-tap as reference
    float w2[6];
    int   i2[6];
    {
        float v = kx * (512.0f / PI_F);
        float q = v * (1.0f / 1024.0f);
        v = (q - floorf(q)) * 1024.0f;
        int base = (int)floorf(v);
        float frac = v - (float)base;
        #pragma unroll
        for (int j = 0; j < 6; ++j) {
            float u = frac + (float)(2 - j);
            float un = u * (1.0f / 3.0f);
            float x = fmaxf(1.0f - un * un, 0.0f);
            w2[j] = i0f(ALPHA_F * sqrtf(x)) * inv_i0a;
            i2[j] = (base - 2 + j + 1024) & 1023;
        }
    }

    float2 acc = make_float2(0.0f, 0.0f);
    #pragma unroll
    for (int b = 0; b < 6; ++b) {
        const char* rowp = (const char*)(GT + i2[b] * 1024);
        float px = 0.0f, py = 0.0f;
        #pragma unroll
        for (int l = 0; l < 4; ++l) {
            float4 f = *(const float4*)(rowp + off1[l]);
            px += w1[2 * l] * f.x + w1[2 * l + 1] * f.z;
            py += w1[2 * l] * f.y + w1[2 * l + 1] * f.w;
        }
        acc.x += w2[b] * px;
        acc.y += w2[b] * py;
    }

    // deposit with (-1)^m sign into radix-3 split layout: m = t = r + 3*tt
    float sgn = (t & 1) ? -1.0f : 1.0f;
    fA[(t % 3) * 256 + (t / 3)] = make_float2(acc.x * sgn, acc.y * sgn);
    __syncthreads();

    float2* F = stockham_b<256, 8, 3, 768, 0>(fA, fB, tw, t);

    int n = t;
    int p = n & 255;
    float2 F0 = F[p], F1 = F[256 + p], F2 = F[512 + p];
    float a1 = TWOPI_F * (float)n * (1.0f / 768.0f);
    float s1, c1, s2, c2;
    __sincosf(a1, &s1, &c1);
    __sincosf(2.0f * a1, &s2, &c2);
    float re = F0.x + (F1.x * c1 - F1.y * s1) + (F2.x * c2 - F2.y * s2);
    float scale = ((n & 1) ? -1.0f : 1.0f) * (1.0f / 768.0f);
    out[a * NDET + n] = re * scale;
}

extern "C" void kernel_launch(void* const* d_in, const int* in_sizes, int n_in,
                              void* d_out, int out_size, void* d_ws, size_t ws_size,
                              hipStream_t stream) {
    (void)in_sizes; (void)n_in; (void)out_size; (void)ws_size;
    const float* image = (const float*)d_in[0];   // (1,1,512,512) f32
    const float* ksp   = (const float*)d_in[1];   // (2, 552960) f32

    float2* U  = (float2*)d_ws;                   // 512*1024 c64  (4 MB)
    float2* GT = U + 512 * 1024;                  // 1024*1024 c64 (8 MB)
    float*  outp = (float*)d_out;

    hipLaunchKernelGGL(fft_rows_kernel,    dim3(512), dim3(512), 0, stream, image, U);
    hipLaunchKernelGGL(fft_cols_kernel,    dim3(512), dim3(512), 0, stream, U, GT);
    hipLaunchKernelGGL(gather_ifft_kernel, dim3(NANG), dim3(768), 0, stream, ksp, GT, outp);
}

// Round 6
// 128.295 us; speedup vs baseline: 1.0160x; 1.0160x over previous
//
#include <hip/hip_runtime.h>
#include <math.h>

#define PI_F     3.14159265358979f
#define TWOPI_F  6.283185307179586f
#define ALPHA_F  14.04f          // 2.34 * J, J = 6
#define NK       552960          // 720 * 768
#define NANG     720
#define NDET     768

#define PAD8(i) ((i) + ((i) >> 3))   // LDS anti-conflict padding (1 c64 per 8)

__device__ __forceinline__ float2 cadd(float2 a, float2 b) { return make_float2(a.x+b.x, a.y+b.y); }
__device__ __forceinline__ float2 csub(float2 a, float2 b) { return make_float2(a.x-b.x, a.y-b.y); }
__device__ __forceinline__ float2 cmul(float2 a, float2 b) { return make_float2(a.x*b.x-a.y*b.y, a.x*b.y+a.y*b.x); }

// ---------- modified Bessel I0, Abramowitz-Stegun 9.8.1/9.8.2 (|eps|<2e-7 rel) ----
__device__ __forceinline__ float i0f(float x) {
    if (x < 3.75f) {
        float t = x * (1.0f / 3.75f);
        float t2 = t * t;
        return 1.0f + t2 * (3.5156229f + t2 * (3.0899424f + t2 * (1.2067492f +
                     t2 * (0.2659732f + t2 * (0.0360768f + t2 * 0.0045813f)))));
    } else {
        float ti = 3.75f / x;
        float p = 0.39894228f + ti * (0.01328592f + ti * (0.00225319f +
                  ti * (-0.00157565f + ti * (0.00916281f + ti * (-0.02057706f +
                  ti * (0.02635537f + ti * (-0.01647633f + ti * 0.00392377f)))))));
        return __expf(x) * rsqrtf(x) * p;
    }
}

// image-domain apodization value for index i (N=512, G=1024): arg>0 always here
__device__ __forceinline__ float apodf(int i, float inv_i0a) {
    float u = ((float)i - 256.0f) * (1.0f / 1024.0f);
    float pj = PI_F * 6.0f * u;
    float arg = ALPHA_F * ALPHA_F - pj * pj;
    float s = sqrtf(arg);
    float F = sinhf(s) / s * (6.0f * inv_i0a);
    return 1.0f / F;
}

// multiply complex v by i^k
__device__ __forceinline__ float2 mul_ipow(float2 v, int k) {
    switch (k & 3) {
        case 0:  return v;
        case 1:  return make_float2(-v.y,  v.x);
        case 2:  return make_float2(-v.x, -v.y);
        default: return make_float2( v.y, -v.x);
    }
}

// radix-4 forward butterfly (W4 = -i), no twiddle
__device__ __forceinline__ void bfly4(float2 a0, float2 a1, float2 a2, float2 a3,
                                      float2& y0, float2& y1, float2& y2, float2& y3) {
    float2 t0 = cadd(a0, a2), t1 = csub(a0, a2);
    float2 t2 = cadd(a1, a3), t3 = csub(a1, a3);
    y0 = cadd(t0, t2);
    y2 = csub(t0, t2);
    y1 = make_float2(t1.x + t3.y, t1.y - t3.x);   // t1 - i*t3
    y3 = make_float2(t1.x - t3.y, t1.y + t3.x);   // t1 + i*t3
}

// ---------- radix-2 Stockham (kept for the small 256-pt inverse FFT) --------------
template<int N, int LOGN, int B, int T>
__device__ __forceinline__ float2* stockham_b(float2* src, float2* dst,
                                              const float2* __restrict__ tw, int tid) {
    constexpr int HALF = N >> 1;
    int log2s = 0;
    for (int n = N; n > 1; n >>= 1, ++log2s) {
        int h = n >> 1;
        int s = 1 << log2s;
        #pragma unroll
        for (int i = tid; i < B * HALF; i += T) {
            int bb = i >> (LOGN - 1);
            int j  = i & (HALF - 1);
            int q = j & (s - 1);
            int p = j >> log2s;
            float2 w = tw[p << log2s];
            float2* S = src + bb * N;
            float2* D = dst + bb * N;
            float2 a  = S[q + (p << log2s)];
            float2 b2 = S[q + ((p + h) << log2s)];
            float2 su = cadd(a, b2);
            float2 di = csub(a, b2);
            D[q + ((2 * p) << log2s)]     = su;
            D[q + ((2 * p + 1) << log2s)] = cmul(di, w);
        }
        __syncthreads();
        float2* t = src; src = dst; dst = t;
    }
    return src;
}

// ---------- stage 1: row FFTs, radix-4 Stockham, 5 stages, 256 threads ------------
// U[row][k] = i^k * sum_c a[row][c] W1024^{c k}; upper 512 inputs zero (folded into
// the first stage, which also applies apodization). Last stage regs->global.
__global__ __launch_bounds__(256) void fft_rows_kernel(const float* __restrict__ img,
                                                       float2* __restrict__ U) {
    __shared__ float2 bA[1152], bB[1152], tw[256];
    int row = blockIdx.x, t = threadIdx.x;
    float sn, cs;
    sincosf(-TWOPI_F * (float)t * (1.0f / 1024.0f), &sn, &cs);
    tw[t] = make_float2(cs, sn);
    float inv_i0a = 1.0f / i0f(ALPHA_F);
    float ar = apodf(row, inv_i0a);

    // stage 1 (s=1, q=0, p=t): x0=a[t], x1=a[t+256], x2=x3=0, inputs real
    {
        float x0 = img[row * 512 + t]       * ar * apodf(t, inv_i0a);
        float x1 = img[row * 512 + t + 256] * ar * apodf(t + 256, inv_i0a);
        float c1 = cs, s1 = sn;
        float c2 = c1 * c1 - s1 * s1, s2 = 2.0f * c1 * s1;
        float c3 = c1 * c2 - s1 * s2, s3 = c1 * s2 + s1 * c2;
        bA[PAD8(4 * t)]     = make_float2(x0 + x1, 0.0f);
        bA[PAD8(4 * t + 1)] = make_float2(x0 * c1 + x1 * s1, x0 * s1 - x1 * c1); // (x0,-x1)*w1
        bA[PAD8(4 * t + 2)] = make_float2((x0 - x1) * c2, (x0 - x1) * s2);
        bA[PAD8(4 * t + 3)] = make_float2(x0 * c3 - x1 * s3, x0 * s3 + x1 * c3); // (x0, x1)*w3
    }
    __syncthreads();

    float2 *S = bA, *D = bB;
    #pragma unroll
    for (int st = 0; st < 3; ++st) {              // stages 2..4: s = 4, 16, 64
        int lg = 2 * (st + 1);
        int s = 1 << lg;
        int q = t & (s - 1), p = t >> lg;
        float2 a0 = S[PAD8(t)],       a1 = S[PAD8(t + 256)];
        float2 a2 = S[PAD8(t + 512)], a3 = S[PAD8(t + 768)];
        float2 y0, y1, y2, y3;
        bfly4(a0, a1, a2, a3, y0, y1, y2, y3);
        float2 w1 = tw[p << lg];
        float2 w2 = cmul(w1, w1), w3 = cmul(w1, w2);
        int ob = q + (p << (lg + 2));
        D[PAD8(ob)]         = y0;
        D[PAD8(ob + s)]     = cmul(y1, w1);
        D[PAD8(ob + 2*s)]   = cmul(y2, w2);
        D[PAD8(ob + 3*s)]   = cmul(y3, w3);
        __syncthreads();
        float2* tmp = S; S = D; D = tmp;
    }
    // stage 5 (s=256, p=0): no twiddle; k = t + 256r; i^(t+256r) == i^t
    {
        float2 a0 = S[PAD8(t)],       a1 = S[PAD8(t + 256)];
        float2 a2 = S[PAD8(t + 512)], a3 = S[PAD8(t + 768)];
        float2 y0, y1, y2, y3;
        bfly4(a0, a1, a2, a3, y0, y1, y2, y3);
        float2* Ur = U + row * 1024;
        Ur[t]       = mul_ipow(y0, t);
        Ur[t + 256] = mul_ipow(y1, t);
        Ur[t + 512] = mul_ipow(y2, t);
        Ur[t + 768] = mul_ipow(y3, t);
    }
}

// ---------- stage 2: col FFTs, radix-4, 2 cols/block, 512 threads -----------------
// GT[k2*1024 + k1] == grid_hat[k1][k2] = i^k1/1024 * sum_r U[r][k2] W1024^{r k1}
#define CSTR 1160   // per-column LDS stride (1152 rounded to shift bank phase)
__global__ __launch_bounds__(512) void fft_cols_kernel(const float2* __restrict__ U,
                                                       float2* __restrict__ GT) {
    __shared__ float2 bA[2 * CSTR], bB[2 * CSTR], tw[256];
    int c0 = blockIdx.x * 2, tid = threadIdx.x;
    int cc = tid & 1, t = tid >> 1;
    float sn, cs;
    sincosf(-TWOPI_F * (float)t * (1.0f / 1024.0f), &sn, &cs);
    if (cc == 0) tw[t] = make_float2(cs, sn);
    float2* myA = bA + cc * CSTR;
    float2* myB = bB + cc * CSTR;

    // stage 1 (s=1, p=t): x0=U[t][c], x1=U[t+256][c], x2=x3=0 (rows 512+ are zero)
    {
        float2 x0 = U[t * 1024 + c0 + cc];
        float2 x1 = U[(t + 256) * 1024 + c0 + cc];
        float2 w1 = make_float2(cs, sn);
        float2 w2 = cmul(w1, w1), w3 = cmul(w1, w2);
        float2 y0 = cadd(x0, x1);
        float2 y2 = csub(x0, x1);
        float2 y1 = make_float2(x0.x + x1.y, x0.y - x1.x);  // x0 - i*x1
        float2 y3 = make_float2(x0.x - x1.y, x0.y + x1.x);  // x0 + i*x1
        myA[PAD8(4 * t)]     = y0;
        myA[PAD8(4 * t + 1)] = cmul(y1, w1);
        myA[PAD8(4 * t + 2)] = cmul(y2, w2);
        myA[PAD8(4 * t + 3)] = cmul(y3, w3);
    }
    __syncthreads();

    float2 *S = myA, *D = myB;
    #pragma unroll
    for (int st = 0; st < 3; ++st) {              // stages 2..4: s = 4, 16, 64
        int lg = 2 * (st + 1);
        int s = 1 << lg;
        int q = t & (s - 1), p = t >> lg;
        float2 a0 = S[PAD8(t)],       a1 = S[PAD8(t + 256)];
        float2 a2 = S[PAD8(t + 512)], a3 = S[PAD8(t + 768)];
        float2 y0, y1, y2, y3;
        bfly4(a0, a1, a2, a3, y0, y1, y2, y3);
        float2 w1 = tw[p << lg];
        float2 w2 = cmul(w1, w1), w3 = cmul(w1, w2);
        int ob = q + (p << (lg + 2));
        D[PAD8(ob)]         = y0;
        D[PAD8(ob + s)]     = cmul(y1, w1);
        D[PAD8(ob + 2*s)]   = cmul(y2, w2);
        D[PAD8(ob + 3*s)]   = cmul(y3, w3);
        __syncthreads();
        float2* tmp = S; S = D; D = tmp;
    }
    // stage 5: k1 = t + 256r; scale + i^k1; store transposed row
    {
        float2 a0 = S[PAD8(t)],       a1 = S[PAD8(t + 256)];
        float2 a2 = S[PAD8(t + 512)], a3 = S[PAD8(t + 768)];
        float2 y0, y1, y2, y3;
        bfly4(a0, a1, a2, a3, y0, y1, y2, y3);
        const float sc = 1.0f / 1024.0f;
        float2* g = GT + (c0 + cc) * 1024;
        float2 v0 = mul_ipow(y0, t), v1 = mul_ipow(y1, t);
        float2 v2 = mul_ipow(y2, t), v3 = mul_ipow(y3, t);
        g[t]       = make_float2(v0.x * sc, v0.y * sc);
        g[t + 256] = make_float2(v1.x * sc, v1.y * sc);
        g[t + 512] = make_float2(v2.x * sc, v2.y * sc);
        g[t + 768] = make_float2(v3.x * sc, v3.y * sc);
    }
}

// ---------- stage 3+4 fused: per-angle KB gather + length-768 inverse FFT ---------
// Block = one angle (XCD-swizzled sectors -> per-XCD L2 locality). 6x6 taps loaded
// into a statically-indexed register array FIRST (36 loads in flight), then
// combined. __launch_bounds__(768,3): VGPR cap ~170 so the batch stays in regs.
__global__ __launch_bounds__(768, 3) void gather_ifft_kernel(const float* __restrict__ ksp,
                                                             const float2* __restrict__ GT,
                                                             float* __restrict__ out) {
    __shared__ float2 fA[768], fB[768], tw[128];
    int t = threadIdx.x;
    int a = (blockIdx.x & 7) * 90 + (blockIdx.x >> 3);   // XCD-contiguous angles
    if (t < 128) {
        float ang = TWOPI_F * (float)t * (1.0f / 256.0f);   // inverse sign
        float sn, cs; sincosf(ang, &sn, &cs);
        tw[t] = make_float2(cs, sn);
    }

    int k = a * NDET + t;
    const float inv_i0a = 1.0f / i0f(ALPHA_F);
    float ky = ksp[k];
    float kx = ksp[NK + k];

    float w1[6], w2[6];
    int   i1[6], i2[6];
    {   // dim 1 (contiguous k1, from ky)
        float v = ky * (512.0f / PI_F);
        float q = v * (1.0f / 1024.0f);
        v = (q - floorf(q)) * 1024.0f;
        int base = (int)floorf(v);
        float frac = v - (float)base;
        #pragma unroll
        for (int j = 0; j < 6; ++j) {
            float u = frac + (float)(2 - j);
            float un = u * (1.0f / 3.0f);
            float x = fmaxf(1.0f - un * un, 0.0f);
            w1[j] = i0f(ALPHA_F * sqrtf(x)) * inv_i0a;
            i1[j] = (base - 2 + j + 1024) & 1023;
        }
    }
    {   // dim 2 (rows of GT, from kx)
        float v = kx * (512.0f / PI_F);
        float q = v * (1.0f / 1024.0f);
        v = (q - floorf(q)) * 1024.0f;
        int base = (int)floorf(v);
        float frac = v - (float)base;
        #pragma unroll
        for (int j = 0; j < 6; ++j) {
            float u = frac + (float)(2 - j);
            float un = u * (1.0f / 3.0f);
            float x = fmaxf(1.0f - un * un, 0.0f);
            w2[j] = i0f(ALPHA_F * sqrtf(x)) * inv_i0a;
            i2[j] = (base - 2 + j + 1024) & 1023;
        }
    }

    // batch all 36 loads (static indices -> VGPRs, maximal MLP), then combine
    float2 gv[36];
    #pragma unroll
    for (int b = 0; b < 6; ++b) {
        const float2* rowp = GT + i2[b] * 1024;
        #pragma unroll
        for (int aa = 0; aa < 6; ++aa)
            gv[b * 6 + aa] = rowp[i1[aa]];
    }
    float accx = 0.0f, accy = 0.0f;
    #pragma unroll
    for (int b = 0; b < 6; ++b) {
        #pragma unroll
        for (int aa = 0; aa < 6; ++aa) {
            float w = w1[aa] * w2[b];
            accx += w * gv[b * 6 + aa].x;
            accy += w * gv[b * 6 + aa].y;
        }
    }

    // deposit with (-1)^m sign into radix-3 split layout: m = t = r + 3*tt
    float sgn = (t & 1) ? -1.0f : 1.0f;
    fA[(t % 3) * 256 + (t / 3)] = make_float2(accx * sgn, accy * sgn);
    __syncthreads();

    float2* F = stockham_b<256, 8, 3, 768>(fA, fB, tw, t);

    int n = t;
    int p = n & 255;
    float2 F0 = F[p], F1 = F[256 + p], F2 = F[512 + p];
    float a1 = TWOPI_F * (float)n * (1.0f / 768.0f);
    float s1, c1, s2, c2;
    __sincosf(a1, &s1, &c1);
    __sincosf(2.0f * a1, &s2, &c2);
    float re = F0.x + (F1.x * c1 - F1.y * s1) + (F2.x * c2 - F2.y * s2);
    float scale = ((n & 1) ? -1.0f : 1.0f) * (1.0f / 768.0f);
    out[a * NDET + n] = re * scale;
}

extern "C" void kernel_launch(void* const* d_in, const int* in_sizes, int n_in,
                              void* d_out, int out_size, void* d_ws, size_t ws_size,
                              hipStream_t stream) {
    (void)in_sizes; (void)n_in; (void)out_size; (void)ws_size;
    const float* image = (const float*)d_in[0];   // (1,1,512,512) f32
    const float* ksp   = (const float*)d_in[1];   // (2, 552960) f32

    float2* U  = (float2*)d_ws;                   // 512*1024 c64  (4 MB)
    float2* GT = U + 512 * 1024;                  // 1024*1024 c64 (8 MB)
    float*  outp = (float*)d_out;

    hipLaunchKernelGGL(fft_rows_kernel,    dim3(512), dim3(256), 0, stream, image, U);
    hipLaunchKernelGGL(fft_cols_kernel,    dim3(512), dim3(512), 0, stream, U, GT);
    hipLaunchKernelGGL(gather_ifft_kernel, dim3(NANG), dim3(768), 0, stream, ksp, GT, outp);
}

// Round 7
// 121.637 us; speedup vs baseline: 1.0716x; 1.0547x over previous
//
#include <hip/hip_runtime.h>
#include <math.h>

#define PI_F     3.14159265358979f
#define TWOPI_F  6.283185307179586f
#define ALPHA_F  14.04f          // 2.34 * J, J = 6
#define NK       552960          // 720 * 768
#define NANG     720
#define NDET     768

#define PAD8(i) ((i) + ((i) >> 3))   // LDS anti-conflict padding (1 c64 per 8)

__device__ __forceinline__ float2 cadd(float2 a, float2 b) { return make_float2(a.x+b.x, a.y+b.y); }
__device__ __forceinline__ float2 csub(float2 a, float2 b) { return make_float2(a.x-b.x, a.y-b.y); }
__device__ __forceinline__ float2 cmul(float2 a, float2 b) { return make_float2(a.x*b.x-a.y*b.y, a.x*b.y+a.y*b.x); }

// ---------- modified Bessel I0, Abramowitz-Stegun 9.8.1/9.8.2 (|eps|<2e-7 rel) ----
__device__ __forceinline__ float i0f(float x) {
    if (x < 3.75f) {
        float t = x * (1.0f / 3.75f);
        float t2 = t * t;
        return 1.0f + t2 * (3.5156229f + t2 * (3.0899424f + t2 * (1.2067492f +
                     t2 * (0.2659732f + t2 * (0.0360768f + t2 * 0.0045813f)))));
    } else {
        float ti = 3.75f / x;
        float p = 0.39894228f + ti * (0.01328592f + ti * (0.00225319f +
                  ti * (-0.00157565f + ti * (0.00916281f + ti * (-0.02057706f +
                  ti * (0.02635537f + ti * (-0.01647633f + ti * 0.00392377f)))))));
        return __expf(x) * rsqrtf(x) * p;
    }
}

// image-domain apodization value for index i (N=512, G=1024): arg>0 always here
__device__ __forceinline__ float apodf(int i, float inv_i0a) {
    float u = ((float)i - 256.0f) * (1.0f / 1024.0f);
    float pj = PI_F * 6.0f * u;
    float arg = ALPHA_F * ALPHA_F - pj * pj;
    float s = sqrtf(arg);
    float F = sinhf(s) / s * (6.0f * inv_i0a);
    return 1.0f / F;
}

// multiply complex v by i^k
__device__ __forceinline__ float2 mul_ipow(float2 v, int k) {
    switch (k & 3) {
        case 0:  return v;
        case 1:  return make_float2(-v.y,  v.x);
        case 2:  return make_float2(-v.x, -v.y);
        default: return make_float2( v.y, -v.x);
    }
}

// radix-4 forward butterfly (W4 = -i), no twiddle
__device__ __forceinline__ void bfly4(float2 a0, float2 a1, float2 a2, float2 a3,
                                      float2& y0, float2& y1, float2& y2, float2& y3) {
    float2 t0 = cadd(a0, a2), t1 = csub(a0, a2);
    float2 t2 = cadd(a1, a3), t3 = csub(a1, a3);
    y0 = cadd(t0, t2);
    y2 = csub(t0, t2);
    y1 = make_float2(t1.x + t3.y, t1.y - t3.x);   // t1 - i*t3
    y3 = make_float2(t1.x - t3.y, t1.y + t3.x);   // t1 + i*t3
}

// ---------- radix-2 Stockham (for the small 256-pt inverse FFT) -------------------
template<int N, int LOGN, int B, int T>
__device__ __forceinline__ float2* stockham_b(float2* src, float2* dst,
                                              const float2* __restrict__ tw, int tid) {
    constexpr int HALF = N >> 1;
    int log2s = 0;
    for (int n = N; n > 1; n >>= 1, ++log2s) {
        int h = n >> 1;
        int s = 1 << log2s;
        #pragma unroll
        for (int i = tid; i < B * HALF; i += T) {
            int bb = i >> (LOGN - 1);
            int j  = i & (HALF - 1);
            int q = j & (s - 1);
            int p = j >> log2s;
            float2 w = tw[p << log2s];
            float2* S = src + bb * N;
            float2* D = dst + bb * N;
            float2 a  = S[q + (p << log2s)];
            float2 b2 = S[q + ((p + h) << log2s)];
            float2 su = cadd(a, b2);
            float2 di = csub(a, b2);
            D[q + ((2 * p) << log2s)]     = su;
            D[q + ((2 * p + 1) << log2s)] = cmul(di, w);
        }
        __syncthreads();
        float2* t = src; src = dst; dst = t;
    }
    return src;
}

// ---------- stage 1: row FFTs, radix-4 Stockham, 5 stages, 256 threads ------------
__global__ __launch_bounds__(256) void fft_rows_kernel(const float* __restrict__ img,
                                                       float2* __restrict__ U) {
    __shared__ float2 bA[1152], bB[1152], tw[256];
    int row = blockIdx.x, t = threadIdx.x;
    float sn, cs;
    sincosf(-TWOPI_F * (float)t * (1.0f / 1024.0f), &sn, &cs);
    tw[t] = make_float2(cs, sn);
    float inv_i0a = 1.0f / i0f(ALPHA_F);
    float ar = apodf(row, inv_i0a);

    // stage 1 (s=1, q=0, p=t): x0=a[t], x1=a[t+256], x2=x3=0, inputs real
    {
        float x0 = img[row * 512 + t]       * ar * apodf(t, inv_i0a);
        float x1 = img[row * 512 + t + 256] * ar * apodf(t + 256, inv_i0a);
        float c1 = cs, s1 = sn;
        float c2 = c1 * c1 - s1 * s1, s2 = 2.0f * c1 * s1;
        float c3 = c1 * c2 - s1 * s2, s3 = c1 * s2 + s1 * c2;
        bA[PAD8(4 * t)]     = make_float2(x0 + x1, 0.0f);
        bA[PAD8(4 * t + 1)] = make_float2(x0 * c1 + x1 * s1, x0 * s1 - x1 * c1);
        bA[PAD8(4 * t + 2)] = make_float2((x0 - x1) * c2, (x0 - x1) * s2);
        bA[PAD8(4 * t + 3)] = make_float2(x0 * c3 - x1 * s3, x0 * s3 + x1 * c3);
    }
    __syncthreads();

    float2 *S = bA, *D = bB;
    #pragma unroll
    for (int st = 0; st < 3; ++st) {              // stages 2..4: s = 4, 16, 64
        int lg = 2 * (st + 1);
        int s = 1 << lg;
        int q = t & (s - 1), p = t >> lg;
        float2 a0 = S[PAD8(t)],       a1 = S[PAD8(t + 256)];
        float2 a2 = S[PAD8(t + 512)], a3 = S[PAD8(t + 768)];
        float2 y0, y1, y2, y3;
        bfly4(a0, a1, a2, a3, y0, y1, y2, y3);
        float2 w1 = tw[p << lg];
        float2 w2 = cmul(w1, w1), w3 = cmul(w1, w2);
        int ob = q + (p << (lg + 2));
        D[PAD8(ob)]         = y0;
        D[PAD8(ob + s)]     = cmul(y1, w1);
        D[PAD8(ob + 2*s)]   = cmul(y2, w2);
        D[PAD8(ob + 3*s)]   = cmul(y3, w3);
        __syncthreads();
        float2* tmp = S; S = D; D = tmp;
    }
    // stage 5 (s=256, p=0): no twiddle; k = t + 256r; i^(t+256r) == i^t
    {
        float2 a0 = S[PAD8(t)],       a1 = S[PAD8(t + 256)];
        float2 a2 = S[PAD8(t + 512)], a3 = S[PAD8(t + 768)];
        float2 y0, y1, y2, y3;
        bfly4(a0, a1, a2, a3, y0, y1, y2, y3);
        float2* Ur = U + row * 1024;
        Ur[t]       = mul_ipow(y0, t);
        Ur[t + 256] = mul_ipow(y1, t);
        Ur[t + 512] = mul_ipow(y2, t);
        Ur[t + 768] = mul_ipow(y3, t);
    }
}

// ---------- stage 2: col FFTs, radix-4, 2 cols/block, 512 threads -----------------
#define CSTR 1160
__global__ __launch_bounds__(512) void fft_cols_kernel(const float2* __restrict__ U,
                                                       float2* __restrict__ GT) {
    __shared__ float2 bA[2 * CSTR], bB[2 * CSTR], tw[256];
    int c0 = blockIdx.x * 2, tid = threadIdx.x;
    int cc = tid & 1, t = tid >> 1;
    float sn, cs;
    sincosf(-TWOPI_F * (float)t * (1.0f / 1024.0f), &sn, &cs);
    if (cc == 0) tw[t] = make_float2(cs, sn);
    float2* myA = bA + cc * CSTR;
    float2* myB = bB + cc * CSTR;

    {
        float2 x0 = U[t * 1024 + c0 + cc];
        float2 x1 = U[(t + 256) * 1024 + c0 + cc];
        float2 w1 = make_float2(cs, sn);
        float2 w2 = cmul(w1, w1), w3 = cmul(w1, w2);
        float2 y0 = cadd(x0, x1);
        float2 y2 = csub(x0, x1);
        float2 y1 = make_float2(x0.x + x1.y, x0.y - x1.x);
        float2 y3 = make_float2(x0.x - x1.y, x0.y + x1.x);
        myA[PAD8(4 * t)]     = y0;
        myA[PAD8(4 * t + 1)] = cmul(y1, w1);
        myA[PAD8(4 * t + 2)] = cmul(y2, w2);
        myA[PAD8(4 * t + 3)] = cmul(y3, w3);
    }
    __syncthreads();

    float2 *S = myA, *D = myB;
    #pragma unroll
    for (int st = 0; st < 3; ++st) {
        int lg = 2 * (st + 1);
        int s = 1 << lg;
        int q = t & (s - 1), p = t >> lg;
        float2 a0 = S[PAD8(t)],       a1 = S[PAD8(t + 256)];
        float2 a2 = S[PAD8(t + 512)], a3 = S[PAD8(t + 768)];
        float2 y0, y1, y2, y3;
        bfly4(a0, a1, a2, a3, y0, y1, y2, y3);
        float2 w1 = tw[p << lg];
        float2 w2 = cmul(w1, w1), w3 = cmul(w1, w2);
        int ob = q + (p << (lg + 2));
        D[PAD8(ob)]         = y0;
        D[PAD8(ob + s)]     = cmul(y1, w1);
        D[PAD8(ob + 2*s)]   = cmul(y2, w2);
        D[PAD8(ob + 3*s)]   = cmul(y3, w3);
        __syncthreads();
        float2* tmp = S; S = D; D = tmp;
    }
    {
        float2 a0 = S[PAD8(t)],       a1 = S[PAD8(t + 256)];
        float2 a2 = S[PAD8(t + 512)], a3 = S[PAD8(t + 768)];
        float2 y0, y1, y2, y3;
        bfly4(a0, a1, a2, a3, y0, y1, y2, y3);
        const float sc = 1.0f / 1024.0f;
        float2* g = GT + (c0 + cc) * 1024;
        float2 v0 = mul_ipow(y0, t), v1 = mul_ipow(y1, t);
        float2 v2 = mul_ipow(y2, t), v3 = mul_ipow(y3, t);
        g[t]       = make_float2(v0.x * sc, v0.y * sc);
        g[t + 256] = make_float2(v1.x * sc, v1.y * sc);
        g[t + 512] = make_float2(v2.x * sc, v2.y * sc);
        g[t + 768] = make_float2(v3.x * sc, v3.y * sc);
    }
}

// ---------- stage 3+4 fused: per-angle KB gather + length-768 inverse FFT ---------
// This round: (1) all 36 taps issued as one batch, pinned by sched_barrier(0) so
// the full batch is in flight before first use (true 36-deep MLP; VGPR check);
// (2) KB weights from a 1025-entry LDS table + lerp (err ~2e-6), computed in the
// load shadow, replacing 12 branchy i0f evals per point.
__global__ __launch_bounds__(768, 3) void gather_ifft_kernel(const float* __restrict__ ksp,
                                                             const float2* __restrict__ GT,
                                                             float* __restrict__ out) {
    __shared__ float2 fA[768], fB[768], tw[128];
    __shared__ float tab[1026];
    int t = threadIdx.x;
    int a = (blockIdx.x & 7) * 90 + (blockIdx.x >> 3);   // XCD-contiguous angles
    const float inv_i0a = 1.0f / i0f(ALPHA_F);
    if (t < 128) {
        float ang = TWOPI_F * (float)t * (1.0f / 256.0f);   // inverse sign
        float sn, cs; sincosf(ang, &sn, &cs);
        tw[t] = make_float2(cs, sn);
    }
    for (int j = t; j < 1025; j += 768) {
        float u = (float)j * (3.0f / 1024.0f);
        float x = fmaxf(1.0f - (u * u) * (1.0f / 9.0f), 0.0f);
        tab[j] = i0f(ALPHA_F * sqrtf(x)) * inv_i0a;
    }
    __syncthreads();                          // tab/tw ready (before load batch!)

    int k = a * NDET + t;
    float ky = ksp[k];
    float kx = ksp[NK + k];

    // indices only (cheap) -------------------------------------------------------
    int i1[6], i2[6];
    float frac1, frac2;
    {
        float v = ky * (512.0f / PI_F);
        float q = v * (1.0f / 1024.0f);
        v = (q - floorf(q)) * 1024.0f;
        int base = (int)floorf(v);
        frac1 = v - (float)base;
        #pragma unroll
        for (int j = 0; j < 6; ++j) i1[j] = (base - 2 + j + 1024) & 1023;
    }
    {
        float v = kx * (512.0f / PI_F);
        float q = v * (1.0f / 1024.0f);
        v = (q - floorf(q)) * 1024.0f;
        int base = (int)floorf(v);
        frac2 = v - (float)base;
        #pragma unroll
        for (int j = 0; j < 6; ++j) i2[j] = (base - 2 + j + 1024) & 1023;
    }

    // batch all 36 loads; sched_barrier pins them before any consumer ------------
    float2 gv[36];
    #pragma unroll
    for (int b = 0; b < 6; ++b) {
        const float2* rowp = GT + i2[b] * 1024;
        #pragma unroll
        for (int aa = 0; aa < 6; ++aa)
            gv[b * 6 + aa] = rowp[i1[aa]];
    }
    __builtin_amdgcn_sched_barrier(0);

    // weights from table (in the load shadow) ------------------------------------
    float w1[6], w2[6];
    #pragma unroll
    for (int j = 0; j < 6; ++j) {
        float u1 = fabsf(frac1 + (float)(2 - j)) * (1024.0f / 3.0f);
        u1 = fminf(u1, 1023.999f);
        int j1 = (int)u1; float f1 = u1 - (float)j1;
        w1[j] = tab[j1] + f1 * (tab[j1 + 1] - tab[j1]);
        float u2 = fabsf(frac2 + (float)(2 - j)) * (1024.0f / 3.0f);
        u2 = fminf(u2, 1023.999f);
        int j2 = (int)u2; float f2 = u2 - (float)j2;
        w2[j] = tab[j2] + f2 * (tab[j2 + 1] - tab[j2]);
    }

    float accx = 0.0f, accy = 0.0f;
    #pragma unroll
    for (int b = 0; b < 6; ++b) {
        float rx = 0.0f, ry = 0.0f;
        #pragma unroll
        for (int aa = 0; aa < 6; ++aa) {
            rx += w1[aa] * gv[b * 6 + aa].x;
            ry += w1[aa] * gv[b * 6 + aa].y;
        }
        accx += w2[b] * rx;
        accy += w2[b] * ry;
    }

    // deposit with (-1)^m sign into radix-3 split layout: m = t = r + 3*tt
    float sgn = (t & 1) ? -1.0f : 1.0f;
    fA[(t % 3) * 256 + (t / 3)] = make_float2(accx * sgn, accy * sgn);
    __syncthreads();

    float2* F = stockham_b<256, 8, 3, 768>(fA, fB, tw, t);

    int n = t;
    int p = n & 255;
    float2 F0 = F[p], F1 = F[256 + p], F2 = F[512 + p];
    float a1 = TWOPI_F * (float)n * (1.0f / 768.0f);
    float s1, c1, s2, c2;
    __sincosf(a1, &s1, &c1);
    __sincosf(2.0f * a1, &s2, &c2);
    float re = F0.x + (F1.x * c1 - F1.y * s1) + (F2.x * c2 - F2.y * s2);
    float scale = ((n & 1) ? -1.0f : 1.0f) * (1.0f / 768.0f);
    out[a * NDET + n] = re * scale;
}

extern "C" void kernel_launch(void* const* d_in, const int* in_sizes, int n_in,
                              void* d_out, int out_size, void* d_ws, size_t ws_size,
                              hipStream_t stream) {
    (void)in_sizes; (void)n_in; (void)out_size; (void)ws_size;
    const float* image = (const float*)d_in[0];   // (1,1,512,512) f32
    const float* ksp   = (const float*)d_in[1];   // (2, 552960) f32

    float2* U  = (float2*)d_ws;                   // 512*1024 c64  (4 MB)
    float2* GT = U + 512 * 1024;                  // 1024*1024 c64 (8 MB)
    float*  outp = (float*)d_out;

    hipLaunchKernelGGL(fft_rows_kernel,    dim3(512), dim3(256), 0, stream, image, U);
    hipLaunchKernelGGL(fft_cols_kernel,    dim3(512), dim3(512), 0, stream, U, GT);
    hipLaunchKernelGGL(gather_ifft_kernel, dim3(NANG), dim3(768), 0, stream, ksp, GT, outp);
}

// Round 8
// 103.228 us; speedup vs baseline: 1.2627x; 1.1783x over previous
//
#include <hip/hip_runtime.h>
#include <math.h>

#define PI_F     3.14159265358979f
#define TWOPI_F  6.283185307179586f
#define ALPHA_F  14.04f          // 2.34 * J, J = 6
#define NK       552960          // 720 * 768
#define NANG     720
#define NDET     768

__device__ __forceinline__ float2 cadd(float2 a, float2 b) { return make_float2(a.x+b.x, a.y+b.y); }
__device__ __forceinline__ float2 csub(float2 a, float2 b) { return make_float2(a.x-b.x, a.y-b.y); }
__device__ __forceinline__ float2 cmul(float2 a, float2 b) { return make_float2(a.x*b.x-a.y*b.y, a.x*b.y+a.y*b.x); }

// ---------- modified Bessel I0, Abramowitz-Stegun 9.8.1/9.8.2 (|eps|<2e-7 rel) ----
__device__ __forceinline__ float i0f(float x) {
    if (x < 3.75f) {
        float t = x * (1.0f / 3.75f);
        float t2 = t * t;
        return 1.0f + t2 * (3.5156229f + t2 * (3.0899424f + t2 * (1.2067492f +
                     t2 * (0.2659732f + t2 * (0.0360768f + t2 * 0.0045813f)))));
    } else {
        float ti = 3.75f / x;
        float p = 0.39894228f + ti * (0.01328592f + ti * (0.00225319f +
                  ti * (-0.00157565f + ti * (0.00916281f + ti * (-0.02057706f +
                  ti * (0.02635537f + ti * (-0.01647633f + ti * 0.00392377f)))))));
        return __expf(x) * rsqrtf(x) * p;
    }
}

// image-domain apodization value for index i (N=512, G=1024): arg>0 always here
__device__ __forceinline__ float apodf(int i, float inv_i0a) {
    float u = ((float)i - 256.0f) * (1.0f / 1024.0f);
    float pj = PI_F * 6.0f * u;
    float arg = ALPHA_F * ALPHA_F - pj * pj;
    float s = sqrtf(arg);
    float F = sinhf(s) / s * (6.0f * inv_i0a);
    return 1.0f / F;
}

// multiply complex v by i^k
__device__ __forceinline__ float2 mul_ipow(float2 v, int k) {
    switch (k & 3) {
        case 0:  return v;
        case 1:  return make_float2(-v.y,  v.x);
        case 2:  return make_float2(-v.x, -v.y);
        default: return make_float2( v.y, -v.x);
    }
}

// ---------- batched radix-2 Stockham FFT in LDS with twiddle table (R3 config) ----
template<int N, int LOGN, int B, int T>
__device__ __forceinline__ float2* stockham_b(float2* src, float2* dst,
                                              const float2* __restrict__ tw, int tid) {
    constexpr int HALF = N >> 1;
    int log2s = 0;
    for (int n = N; n > 1; n >>= 1, ++log2s) {
        int h = n >> 1;
        int s = 1 << log2s;
        #pragma unroll
        for (int i = tid; i < B * HALF; i += T) {
            int bb = i >> (LOGN - 1);
            int j  = i & (HALF - 1);
            int q = j & (s - 1);
            int p = j >> log2s;
            float2 w = tw[p << log2s];
            float2* S = src + bb * N;
            float2* D = dst + bb * N;
            float2 a  = S[q + (p << log2s)];
            float2 b2 = S[q + ((p + h) << log2s)];
            float2 su = cadd(a, b2);
            float2 di = csub(a, b2);
            D[q + ((2 * p) << log2s)]     = su;
            D[q + ((2 * p + 1) << log2s)] = cmul(di, w);
        }
        __syncthreads();
        float2* t = src; src = dst; dst = t;
    }
    return src;
}

// ---------- stage 1: row FFTs (R3 exact) ------------------------------------------
__global__ __launch_bounds__(256) void fft_rows_kernel(const float* __restrict__ img,
                                                       float2* __restrict__ U) {
    __shared__ float2 bA[1024], bB[1024], tw[512];
    int r = blockIdx.x, t = threadIdx.x;
    for (int j = t; j < 512; j += 256) {
        float ang = -TWOPI_F * (float)j * (1.0f / 1024.0f);
        float sn, cs; sincosf(ang, &sn, &cs);
        tw[j] = make_float2(cs, sn);
    }
    float inv_i0a = 1.0f / i0f(ALPHA_F);
    float ar = apodf(r, inv_i0a);
    for (int c = t; c < 512; c += 256)
        bA[c] = make_float2(img[r * 512 + c] * ar * apodf(c, inv_i0a), 0.0f);
    for (int c = t + 512; c < 1024; c += 256)
        bA[c] = make_float2(0.0f, 0.0f);
    __syncthreads();
    float2* res = stockham_b<1024, 10, 1, 256>(bA, bB, tw, t);
    for (int k = t; k < 1024; k += 256)
        U[r * 1024 + k] = mul_ipow(res[k], k);
}

// ---------- stage 2: col FFTs (R3 exact), 4 columns/block -------------------------
__global__ __launch_bounds__(512) void fft_cols_kernel(const float2* __restrict__ U,
                                                       float2* __restrict__ GT) {
    __shared__ float2 bA[4096], bB[4096], tw[512];
    int c0 = blockIdx.x * 4, t = threadIdx.x;
    if (t < 512) {
        float ang = -TWOPI_F * (float)t * (1.0f / 1024.0f);
        float sn, cs; sincosf(ang, &sn, &cs);
        tw[t] = make_float2(cs, sn);
    }
    #pragma unroll
    for (int it = 0; it < 4; ++it) {
        int i = t + it * 512;
        int rr = i >> 2, cc = i & 3;
        bA[cc * 1024 + rr] = U[rr * 1024 + c0 + cc];
    }
    #pragma unroll
    for (int it = 0; it < 4; ++it) {
        int i = t + it * 512;
        bA[(i >> 9) * 1024 + 512 + (i & 511)] = make_float2(0.0f, 0.0f);
    }
    __syncthreads();
    float2* res = stockham_b<1024, 10, 4, 512>(bA, bB, tw, t);
    const float sc = 1.0f / 1024.0f;
    #pragma unroll
    for (int it = 0; it < 8; ++it) {
        int i = t + it * 512;
        int cc = i >> 10, k1 = i & 1023;
        float2 v = mul_ipow(res[cc * 1024 + k1], k1);
        GT[(c0 + cc) * 1024 + k1] = make_float2(v.x * sc, v.y * sc);
    }
}

// ---------- stage 3+4 fused: quad-lane cooperative KB gather + 768-pt iFFT --------
__global__ __launch_bounds__(768) void gather_ifft_kernel(const float* __restrict__ ksp,
                                                          const float2* __restrict__ GT,
                                                          float* __restrict__ out) {
    __shared__ float2 fA[768], fB[768], tw[128];
    __shared__ float tab[1026];
    int t = threadIdx.x;
    int a = (blockIdx.x & 7) * 90 + (blockIdx.x >> 3);   // XCD-contiguous angles
    const float inv_i0a = 1.0f / i0f(ALPHA_F);
    if (t < 128) {
        float ang = TWOPI_F * (float)t * (1.0f / 256.0f);
        float sn, cs; sincosf(ang, &sn, &cs);
        tw[t] = make_float2(cs, sn);
    }
    for (int j = t; j < 1026; j += 768) {
        float u = (float)j * (3.0f / 1024.0f);
        float x = fmaxf(1.0f - (u * u) * (1.0f / 9.0f), 0.0f);
        tab[j] = i0f(ALPHA_F * sqrtf(x)) * inv_i0a;
    }
    __syncthreads();

    int lane = t & 63, wid = t >> 6;          // 12 waves
    int l = lane & 3, dsub = lane >> 2;       // quad slot / detector-sub
    float m0 = (float)(2 * l), m1 = (float)(2 * l + 1);

    #pragma unroll
    for (int pass = 0; pass < 4; ++pass) {
        int det = pass * 192 + wid * 16 + dsub;
        int kk = a * NDET + det;
        float ky = ksp[kk];
        float kx = ksp[NK + kk];

        float v1 = ky * (512.0f / PI_F);
        float q1 = v1 * (1.0f / 1024.0f);
        v1 = (q1 - floorf(q1)) * 1024.0f;
        int b1 = (int)floorf(v1);
        int e  = (b1 - 2) & ~1;
        float fe = v1 - (float)e;                        // in [2,4)
        int col8 = ((e + 2 * l) & 1023) * 8;

        float ua = fabsf(fe - m0), ub = fabsf(fe - m1);
        float w1a, w1b;
        {
            float uu = fminf(ua, 3.0f) * (1024.0f / 3.0f);
            int jj = (int)uu; float ff = uu - (float)jj;
            float w = tab[jj] + ff * (tab[jj + 1] - tab[jj]);
            w1a = (ua < 3.0f) ? w : 0.0f;
        }
        {
            float uu = fminf(ub, 3.0f) * (1024.0f / 3.0f);
            int jj = (int)uu; float ff = uu - (float)jj;
            float w = tab[jj] + ff * (tab[jj + 1] - tab[jj]);
            w1b = (ub < 3.0f) ? w : 0.0f;
        }

        float v2 = kx * (512.0f / PI_F);
        float q2 = v2 * (1.0f / 1024.0f);
        v2 = (q2 - floorf(q2)) * 1024.0f;
        int b2 = (int)floorf(v2);
        float frac2 = v2 - (float)b2;

        float accx = 0.0f, accy = 0.0f;
        #pragma unroll
        for (int b = 0; b < 6; ++b) {
            int row = (b2 - 2 + b + 1024) & 1023;
            float u2 = fabsf(frac2 + (float)(2 - b)) * (1024.0f / 3.0f);
            int j2 = (int)u2; float f2 = u2 - (float)j2;
            float w2 = tab[j2] + f2 * (tab[j2 + 1] - tab[j2]);
            float4 f = *(const float4*)((const char*)GT + row * 8192 + col8);
            accx += w2 * (w1a * f.x + w1b * f.z);
            accy += w2 * (w1a * f.y + w1b * f.w);
        }

        accx += __shfl_xor(accx, 1);
        accx += __shfl_xor(accx, 2);
        accy += __shfl_xor(accy, 1);
        accy += __shfl_xor(accy, 2);

        if (l == 0) {
            float sgn = (det & 1) ? -1.0f : 1.0f;
            fA[(det % 3) * 256 + (det / 3)] = make_float2(accx * sgn, accy * sgn);
        }
    }
    __syncthreads();

    float2* F = stockham_b<256, 8, 3, 768>(fA, fB, tw, t);

    int n = t;
    int p = n & 255;
    float2 F0 = F[p], F1 = F[256 + p], F2 = F[512 + p];
    float a1 = TWOPI_F * (float)n * (1.0f / 768.0f);
    float s1, c1, s2, c2;
    __sincosf(a1, &s1, &c1);
    __sincosf(2.0f * a1, &s2, &c2);
    float re = F0.x + (F1.x * c1 - F1.y * s1) + (F2.x * c2 - F2.y * s2);
    float scale = ((n & 1) ? -1.0f : 1.0f) * (1.0f / 768.0f);
    out[a * NDET + n] = re * scale;
}

extern "C" void kernel_launch(void* const* d_in, const int* in_sizes, int n_in,
                              void* d_out, int out_size, void* d_ws, size_t ws_size,
                              hipStream_t stream) {
    (void)in_sizes; (void)n_in; (void)out_size; (void)ws_size;
    const float* image = (const float*)d_in[0];   // (1,1,512,512) f32
    const float* ksp   = (const float*)d_in[1];   // (2, 552960) f32

    float2* U  = (float2*)d_ws;                   // 512*1024 c64  (4 MB)
    float2* GT = U + 512 * 1024;                  // 1024*1024 c64 (8 MB)
    float*  outp = (float*)d_out;

    hipLaunchKernelGGL(fft_rows_kernel,    dim3(512), dim3(256), 0, stream, image, U);
    hipLaunchKernelGGL(fft_cols_kernel,    dim3(256), dim3(512), 0, stream, U, GT);
    hipLaunchKernelGGL(gather_ifft_kernel, dim3(NANG), dim3(768), 0, stream, ksp, GT, outp);
}

// Round 9
// 95.282 us; speedup vs baseline: 1.3680x; 1.0834x over previous
//
#include <hip/hip_runtime.h>
#include <math.h>

#define PI_F     3.14159265358979f
#define TWOPI_F  6.283185307179586f
#define ALPHA_F  14.04f          // 2.34 * J, J = 6
#define NK       552960          // 720 * 768
#define NANG     720
#define NDET     768

__device__ __forceinline__ float2 cadd(float2 a, float2 b) { return make_float2(a.x+b.x, a.y+b.y); }
__device__ __forceinline__ float2 csub(float2 a, float2 b) { return make_float2(a.x-b.x, a.y-b.y); }
__device__ __forceinline__ float2 cmul(float2 a, float2 b) { return make_float2(a.x*b.x-a.y*b.y, a.x*b.y+a.y*b.x); }

// ---------- modified Bessel I0, Abramowitz-Stegun 9.8.1/9.8.2 (|eps|<2e-7 rel) ----
__device__ __forceinline__ float i0f(float x) {
    if (x < 3.75f) {
        float t = x * (1.0f / 3.75f);
        float t2 = t * t;
        return 1.0f + t2 * (3.5156229f + t2 * (3.0899424f + t2 * (1.2067492f +
                     t2 * (0.2659732f + t2 * (0.0360768f + t2 * 0.0045813f)))));
    } else {
        float ti = 3.75f / x;
        float p = 0.39894228f + ti * (0.01328592f + ti * (0.00225319f +
                  ti * (-0.00157565f + ti * (0.00916281f + ti * (-0.02057706f +
                  ti * (0.02635537f + ti * (-0.01647633f + ti * 0.00392377f)))))));
        return __expf(x) * rsqrtf(x) * p;
    }
}

// KB tap weight at |u| (u in grid units, support |u|<3)
__device__ __forceinline__ float kbw(float u, float inv_i0a) {
    float x = fmaxf(1.0f - (u * u) * (1.0f / 9.0f), 0.0f);
    return i0f(ALPHA_F * sqrtf(x)) * inv_i0a;
}

// image-domain apodization value for index i (N=512, G=1024): arg>0 always here
__device__ __forceinline__ float apodf(int i, float inv_i0a) {
    float u = ((float)i - 256.0f) * (1.0f / 1024.0f);
    float pj = PI_F * 6.0f * u;
    float arg = ALPHA_F * ALPHA_F - pj * pj;
    float s = sqrtf(arg);
    float F = sinhf(s) / s * (6.0f * inv_i0a);
    return 1.0f / F;
}

// multiply complex v by i^k
__device__ __forceinline__ float2 mul_ipow(float2 v, int k) {
    switch (k & 3) {
        case 0:  return v;
        case 1:  return make_float2(-v.y,  v.x);
        case 2:  return make_float2(-v.x, -v.y);
        default: return make_float2( v.y, -v.x);
    }
}

// ---------- batched radix-2 Stockham FFT in LDS with twiddle table ----------------
template<int N, int LOGN, int B, int T>
__device__ __forceinline__ float2* stockham_b(float2* src, float2* dst,
                                              const float2* __restrict__ tw, int tid) {
    constexpr int HALF = N >> 1;
    int log2s = 0;
    for (int n = N; n > 1; n >>= 1, ++log2s) {
        int h = n >> 1;
        int s = 1 << log2s;
        #pragma unroll
        for (int i = tid; i < B * HALF; i += T) {
            int bb = i >> (LOGN - 1);
            int j  = i & (HALF - 1);
            int q = j & (s - 1);
            int p = j >> log2s;
            float2 w = tw[p << log2s];
            float2* S = src + bb * N;
            float2* D = dst + bb * N;
            float2 a  = S[q + (p << log2s)];
            float2 b2 = S[q + ((p + h) << log2s)];
            float2 su = cadd(a, b2);
            float2 di = csub(a, b2);
            D[q + ((2 * p) << log2s)]     = su;
            D[q + ((2 * p + 1) << log2s)] = cmul(di, w);
        }
        __syncthreads();
        float2* t = src; src = dst; dst = t;
    }
    return src;
}

// ---------- stage 1: row FFTs, TWO REAL ROWS PER COMPLEX FFT (Hermitian pack) -----
// x[c] = ar0*a[2r][c]*ac + i*ar1*a[2r+1][c]*ac; X = FFT1024(x zero-padded).
// A0[k] = (X[k]+conj X[-k])/2, A1[k] = -i(X[k]-conj X[-k])/2;
// U[2r][k] = i^k A0[k], U[2r+1][k] = i^k A1[k].
__global__ __launch_bounds__(256) void fft_rows_kernel(const float* __restrict__ img,
                                                       float2* __restrict__ U) {
    __shared__ float2 bA[1024], bB[1024], tw[512];
    int r0 = blockIdx.x * 2, t = threadIdx.x;
    for (int j = t; j < 512; j += 256) {
        float ang = -TWOPI_F * (float)j * (1.0f / 1024.0f);
        float sn, cs; sincosf(ang, &sn, &cs);
        tw[j] = make_float2(cs, sn);
    }
    float inv_i0a = 1.0f / i0f(ALPHA_F);
    float ar0 = apodf(r0, inv_i0a);
    float ar1 = apodf(r0 + 1, inv_i0a);
    for (int c = t; c < 512; c += 256) {
        float ac = apodf(c, inv_i0a);
        bA[c] = make_float2(img[r0 * 512 + c] * ar0 * ac,
                            img[(r0 + 1) * 512 + c] * ar1 * ac);
    }
    for (int c = t + 512; c < 1024; c += 256)
        bA[c] = make_float2(0.0f, 0.0f);
    __syncthreads();
    float2* res = stockham_b<1024, 10, 1, 256>(bA, bB, tw, t);
    for (int k = t; k < 1024; k += 256) {
        float2 X0 = res[k];
        float2 Xm = res[(1024 - k) & 1023];
        float2 A0 = make_float2(0.5f * (X0.x + Xm.x), 0.5f * (X0.y - Xm.y));
        float2 A1 = make_float2(0.5f * (X0.y + Xm.y), -0.5f * (X0.x - Xm.x));
        U[r0 * 1024 + k]       = mul_ipow(A0, k);
        U[(r0 + 1) * 1024 + k] = mul_ipow(A1, k);
    }
}

// ---------- stage 2: col FFTs for k2=0..515 only + Hermitian mirror store ---------
// GT[k2*1024+k1] == grid_hat[k1][k2]; grid_hat Hermitian =>
// GT[1024-c][(1024-k1)&1023] = conj(GT[c][k1]) for c in [1,508] covers k2=516..1023.
__global__ __launch_bounds__(512) void fft_cols_kernel(const float2* __restrict__ U,
                                                       float2* __restrict__ GT) {
    __shared__ float2 bA[4096], bB[4096], tw[512];
    int c0 = blockIdx.x * 4, t = threadIdx.x;
    if (t < 512) {
        float ang = -TWOPI_F * (float)t * (1.0f / 1024.0f);
        float sn, cs; sincosf(ang, &sn, &cs);
        tw[t] = make_float2(cs, sn);
    }
    #pragma unroll
    for (int it = 0; it < 4; ++it) {               // rows 0..511, 4 cols: coalesced
        int i = t + it * 512;
        int rr = i >> 2, cc = i & 3;
        bA[cc * 1024 + rr] = U[rr * 1024 + c0 + cc];
    }
    #pragma unroll
    for (int it = 0; it < 4; ++it) {               // rows 512..1023: zero
        int i = t + it * 512;
        bA[(i >> 9) * 1024 + 512 + (i & 511)] = make_float2(0.0f, 0.0f);
    }
    __syncthreads();
    float2* res = stockham_b<1024, 10, 4, 512>(bA, bB, tw, t);
    const float sc = 1.0f / 1024.0f;
    #pragma unroll
    for (int it = 0; it < 8; ++it) {
        int i = t + it * 512;
        int cc = i >> 10, k1 = i & 1023;
        int ccg = c0 + cc;
        float2 v = mul_ipow(res[cc * 1024 + k1], k1);
        v = make_float2(v.x * sc, v.y * sc);
        GT[ccg * 1024 + k1] = v;
        if (ccg >= 1 && ccg <= 508)                // mirror rows 516..1023
            GT[(1024 - ccg) * 1024 + ((1024 - k1) & 1023)] = make_float2(v.x, -v.y);
    }
}

// ---------- stage 3+4 fused: quad-lane cooperative KB gather + 768-pt iFFT --------
// (value,delta) weight table: each weight = 1 LDS b64 read + fmaf.
__global__ __launch_bounds__(768) void gather_ifft_kernel(const float* __restrict__ ksp,
                                                          const float2* __restrict__ GT,
                                                          float* __restrict__ out) {
    __shared__ float2 fA[768], fB[768], tw[128];
    __shared__ float2 tab2[1026];
    int t = threadIdx.x;
    int a = (blockIdx.x & 7) * 90 + (blockIdx.x >> 3);   // XCD-contiguous angles
    const float inv_i0a = 1.0f / i0f(ALPHA_F);
    if (t < 128) {
        float ang = TWOPI_F * (float)t * (1.0f / 256.0f);
        float sn, cs; sincosf(ang, &sn, &cs);
        tw[t] = make_float2(cs, sn);
    }
    for (int j = t; j < 1026; j += 768) {
        float w0 = kbw((float)j * (3.0f / 1024.0f), inv_i0a);
        float w1 = kbw((float)(j + 1) * (3.0f / 1024.0f), inv_i0a);
        tab2[j] = make_float2(w0, w1 - w0);
    }
    __syncthreads();

    int lane = t & 63, wid = t >> 6;          // 12 waves
    int l = lane & 3, dsub = lane >> 2;       // quad slot / detector-sub
    float m0 = (float)(2 * l), m1 = (float)(2 * l + 1);

    #pragma unroll
    for (int pass = 0; pass < 4; ++pass) {
        int det = pass * 192 + wid * 16 + dsub;
        int kk = a * NDET + det;
        float ky = ksp[kk];
        float kx = ksp[NK + kk];

        float v1 = ky * (512.0f / PI_F);
        float q1 = v1 * (1.0f / 1024.0f);
        v1 = (q1 - floorf(q1)) * 1024.0f;
        int b1 = (int)floorf(v1);
        int e  = (b1 - 2) & ~1;
        float fe = v1 - (float)e;                        // in [2,4)
        int col8 = ((e + 2 * l) & 1023) * 8;

        float ua = fabsf(fe - m0), ub = fabsf(fe - m1);
        float w1a, w1b;
        {
            float uu = fminf(ua, 3.0f) * (1024.0f / 3.0f);
            int jj = (int)uu; float ff = uu - (float)jj;
            float2 td = tab2[jj];
            w1a = (ua < 3.0f) ? fmaf(ff, td.y, td.x) : 0.0f;
        }
        {
            float uu = fminf(ub, 3.0f) * (1024.0f / 3.0f);
            int jj = (int)uu; float ff = uu - (float)jj;
            float2 td = tab2[jj];
            w1b = (ub < 3.0f) ? fmaf(ff, td.y, td.x) : 0.0f;
        }

        float v2 = kx * (512.0f / PI_F);
        float q2 = v2 * (1.0f / 1024.0f);
        v2 = (q2 - floorf(q2)) * 1024.0f;
        int b2 = (int)floorf(v2);
        float frac2 = v2 - (float)b2;

        float accx = 0.0f, accy = 0.0f;
        #pragma unroll
        for (int b = 0; b < 6; ++b) {
            int row = (b2 - 2 + b + 1024) & 1023;
            float u2 = fabsf(frac2 + (float)(2 - b)) * (1024.0f / 3.0f);
            int j2 = (int)u2; float f2 = u2 - (float)j2;
            float2 td = tab2[j2];
            float w2 = fmaf(f2, td.y, td.x);
            float4 f = *(const float4*)((const char*)GT + row * 8192 + col8);
            accx += w2 * (w1a * f.x + w1b * f.z);
            accy += w2 * (w1a * f.y + w1b * f.w);
        }

        accx += __shfl_xor(accx, 1);
        accx += __shfl_xor(accx, 2);
        accy += __shfl_xor(accy, 1);
        accy += __shfl_xor(accy, 2);

        if (l == 0) {
            float sgn = (det & 1) ? -1.0f : 1.0f;
            fA[(det % 3) * 256 + (det / 3)] = make_float2(accx * sgn, accy * sgn);
        }
    }
    __syncthreads();

    float2* F = stockham_b<256, 8, 3, 768>(fA, fB, tw, t);

    int n = t;
    int p = n & 255;
    float2 F0 = F[p], F1 = F[256 + p], F2 = F[512 + p];
    float a1 = TWOPI_F * (float)n * (1.0f / 768.0f);
    float s1, c1, s2, c2;
    __sincosf(a1, &s1, &c1);
    __sincosf(2.0f * a1, &s2, &c2);
    float re = F0.x + (F1.x * c1 - F1.y * s1) + (F2.x * c2 - F2.y * s2);
    float scale = ((n & 1) ? -1.0f : 1.0f) * (1.0f / 768.0f);
    out[a * NDET + n] = re * scale;
}

extern "C" void kernel_launch(void* const* d_in, const int* in_sizes, int n_in,
                              void* d_out, int out_size, void* d_ws, size_t ws_size,
                              hipStream_t stream) {
    (void)in_sizes; (void)n_in; (void)out_size; (void)ws_size;
    const float* image = (const float*)d_in[0];   // (1,1,512,512) f32
    const float* ksp   = (const float*)d_in[1];   // (2, 552960) f32

    float2* U  = (float2*)d_ws;                   // 512*1024 c64  (4 MB)
    float2* GT = U + 512 * 1024;                  // 1024*1024 c64 (8 MB)
    float*  outp = (float*)d_out;

    hipLaunchKernelGGL(fft_rows_kernel,    dim3(256), dim3(256), 0, stream, image, U);
    hipLaunchKernelGGL(fft_cols_kernel,    dim3(129), dim3(512), 0, stream, U, GT);
    hipLaunchKernelGGL(gather_ifft_kernel, dim3(NANG), dim3(768), 0, stream, ksp, GT, outp);
}